// Round 19
// baseline (196.235 us; speedup 1.0000x reference)
//
#include <hip/hip_runtime.h>
#include <stdint.h>

#define D_FEAT 128
#define D_OUT  64
#define BSH 7              // 128 nodes per bucket
#define MAXB 1024          // max buckets (N <= 131072)
#define BCAP 4096          // fixed bucket capacity (mean 2046 + 45 sigma)
#define H1P  136           // h1 LDS row pitch in ushorts (272 B)
#define SCAT_BLKS 512      // prep-kernel blocks doing edge scatter

typedef __attribute__((ext_vector_type(8))) short short8;   // 8 bf16 (4 VGPRs)
typedef __attribute__((ext_vector_type(8))) ushort ushort8; // 8 bf16
typedef __attribute__((ext_vector_type(4))) float f32x4;
typedef __attribute__((ext_vector_type(2))) float f32x2;

// ---------------------------------------------------------------------------
// helpers
// ---------------------------------------------------------------------------
__device__ __forceinline__ ushort f2bf(float f) {            // RNE f32->bf16
  uint32_t u = __float_as_uint(f);
  return (ushort)((u + 0x7FFFu + ((u >> 16) & 1u)) >> 16);
}
__device__ __forceinline__ float bf2f(ushort v) {
  return __uint_as_float((uint32_t)v << 16);
}
// accumulate a packed bf16 pair into an f32x2 (one v_pk_add_f32).
__device__ __forceinline__ void acc2(f32x2& a, uint32_t w) {
  f32x2 t;
  t.x = __uint_as_float(w << 16);
  t.y = __uint_as_float(w);
  a += t;
}
// accumulate 4 fp8 (one u32) into two f32x2 via native cvt
__device__ __forceinline__ void accq(f32x2& a, f32x2& b, uint32_t w) {
  a += __builtin_amdgcn_cvt_pk_f32_fp8(w, false);
  b += __builtin_amdgcn_cvt_pk_f32_fp8(w, true);
}

__device__ __forceinline__ void threefry2x32(uint32_t k0, uint32_t k1,
                                             uint32_t& x0, uint32_t& x1) {
  uint32_t k2 = k0 ^ k1 ^ 0x1BD11BDAu;
#define TF_ROT(r) { x0 += x1; x1 = (x1 << (r)) | (x1 >> (32 - (r))); x1 ^= x0; }
  x0 += k0; x1 += k1;
  TF_ROT(13) TF_ROT(15) TF_ROT(26) TF_ROT(6)
  x0 += k1; x1 += k2 + 1u;
  TF_ROT(17) TF_ROT(29) TF_ROT(16) TF_ROT(24)
  x0 += k2; x1 += k0 + 2u;
  TF_ROT(13) TF_ROT(15) TF_ROT(26) TF_ROT(6)
  x0 += k0; x1 += k1 + 3u;
  TF_ROT(17) TF_ROT(29) TF_ROT(16) TF_ROT(24)
  x0 += k1; x1 += k2 + 4u;
  TF_ROT(13) TF_ROT(15) TF_ROT(26) TF_ROT(6)
  x0 += k2; x1 += k0 + 5u;
#undef TF_ROT
}

__device__ __forceinline__ bool keep_bit(uint32_t i) {
  uint32_t t0 = 0u, t1 = i;
  threefry2x32(0u, 42u, t0, t1);
  return (((t0 ^ t1) >> 31) == 0u);
}

__device__ __forceinline__ int load_dst(const void* ei, int is64, long E, long e) {
  return is64 ? (int)((const long long*)ei)[E + e] : ((const int*)ei)[E + e];
}
__device__ __forceinline__ int load_src(const void* ei, int is64, long E, long e) {
  return is64 ? (int)((const long long*)ei)[e] : ((const int*)ei)[e];
}

// ---------------------------------------------------------------------------
// prep mega-kernel (grid-partitioned independent work):
//   blocks [0, SCAT_BLKS)            : edge scatter into fixed-cap buckets
//   blocks [SCAT_BLKS, +nConv)       : x -> bf16 xb + fp8 xq
//   next 128 / 32 / 32 blocks        : pack w1 / w2l / w2r
//   last block                       : zero phantom rows of xb/xq
// bucketOff[] must be memset to 0 beforehand (cursors are bucket-relative).
// ---------------------------------------------------------------------------
__global__ __launch_bounds__(256) void prep_kernel(
    const float4* __restrict__ x, const void* __restrict__ ei,
    ushort* __restrict__ xb, uint8_t* __restrict__ xq,
    const float* __restrict__ W1l, const float* __restrict__ W1r,
    const float* __restrict__ W2l, const float* __restrict__ W2r,
    ushort* __restrict__ w1t, ushort* __restrict__ w2lt, ushort* __restrict__ w2rt,
    int* __restrict__ bucketOff, uint32_t* __restrict__ packed,
    long E, long n4, int N, int nbuck, int chunkE, int nConv) {
  const int b = blockIdx.x;
  const int tid = threadIdx.x;

  if (b < SCAT_BLKS) {
    // ---- edge scatter ----
    __shared__ int cnt[MAXB];
    __shared__ int base[MAXB];
    __shared__ int cur[MAXB];
    __shared__ int is64_s;
    if (tid < 64) {
      uint32_t v = ((const uint32_t*)ei)[2 * tid + 1];
      unsigned long long nz = __ballot(v != 0u);
      if (tid == 0) is64_s = (nz == 0ull) ? 1 : 0;
    }
    for (int i = tid; i < nbuck; i += 256) { cnt[i] = 0; cur[i] = 0; }
    __syncthreads();
    const int is64 = is64_s;
    long beg = (long)b * chunkE;
    long end = beg + chunkE; if (end > E) end = E;
    for (long e = beg + tid; e < end; e += 256)
      atomicAdd(&cnt[load_dst(ei, is64, E, e) >> BSH], 1);
    __syncthreads();
    for (int i = tid; i < nbuck; i += 256)
      base[i] = cnt[i] ? atomicAdd(&bucketOff[i], cnt[i]) : 0;
    __syncthreads();
    for (long e = beg + tid; e < end; e += 256) {
      int dst = load_dst(ei, is64, E, e);
      int src = load_src(ei, is64, E, e);
      int bk = dst >> BSH;
      int off = atomicAdd(&cur[bk], 1);
      packed[(long)bk * BCAP + base[bk] + off] =
          ((uint32_t)src << BSH) | (uint32_t)(dst & ((1 << BSH) - 1));
    }
  } else if (b < SCAT_BLKS + nConv) {
    // ---- convert x -> bf16 + fp8 ----
    long i = (long)(b - SCAT_BLKS) * 256 + tid;
    if (i < n4) {
      float4 v = x[i];
      ushort4 o = {f2bf(v.x), f2bf(v.y), f2bf(v.z), f2bf(v.w)};
      *(ushort4*)(xb + i * 4) = o;
      int p = 0;
      p = __builtin_amdgcn_cvt_pk_fp8_f32(v.x, v.y, p, false);
      p = __builtin_amdgcn_cvt_pk_fp8_f32(v.z, v.w, p, true);
      ((uint32_t*)xq)[i] = (uint32_t)p;
    }
  } else if (b < SCAT_BLKS + nConv + 128) {
    // ---- pack w1: w1t[j][k] ----
    int idx = (b - SCAT_BLKS - nConv) * 256 + tid;   // 128*256
    int j = idx >> 8, k = idx & 255;
    float v = (k < 128) ? W1l[k * 128 + j] : W1r[(k - 128) * 128 + j];
    w1t[j * 256 + k] = f2bf(v);
  } else if (b < SCAT_BLKS + nConv + 128 + 32) {
    int idx = (b - SCAT_BLKS - nConv - 128) * 256 + tid;   // 64*128
    int j = idx >> 7, k = idx & 127;
    w2lt[j * 128 + k] = f2bf(W2l[k * 64 + j]);
  } else if (b < SCAT_BLKS + nConv + 128 + 64) {
    int idx = (b - SCAT_BLKS - nConv - 160) * 256 + tid;
    int j = idx >> 7, k = idx & 127;
    w2rt[j * 128 + k] = f2bf(W2r[k * 64 + j]);
  } else {
    // ---- zero phantom rows (xb bf16 256 B, xq fp8 128 B) ----
    if (tid < 16)
      *(ushort8*)(xb + (long)N * D_FEAT + tid * 8) = (ushort8){0,0,0,0,0,0,0,0};
    else if (tid < 24)
      *(uint4*)(xq + (long)N * D_FEAT + (tid - 16) * 16) = (uint4){0,0,0,0};
  }
}

// ---------------------------------------------------------------------------
// per bucket: stage to LDS -> local hist+scan -> rowptr/rowend/invd,
// then write col IN PLACE over packed (values become src ids)
// ---------------------------------------------------------------------------
__global__ __launch_bounds__(256) void bucket_build(
    uint32_t* __restrict__ packed, const int* __restrict__ bucketOff,
    int* __restrict__ rowptr, int* __restrict__ rowend,
    float* __restrict__ invd, int N) {
  __shared__ uint32_t sp[BCAP];
  __shared__ int lcnt[1 << BSH];
  __shared__ int lbase[1 << BSH];
  __shared__ int lcur[1 << BSH];
  const int b = blockIdx.x;
  const int tid = threadIdx.x;
  const int beg = b * BCAP;
  const int cnt = bucketOff[b];
  for (int i = tid; i < cnt; i += 256) sp[i] = packed[beg + i];
  if (tid < 128) { lcnt[tid] = 0; lcur[tid] = 0; }
  __syncthreads();
  for (int i = tid; i < cnt; i += 256)
    atomicAdd(&lcnt[sp[i] & 127], 1);
  __syncthreads();
  if (tid < 128) lbase[tid] = lcnt[tid];
  __syncthreads();
  for (int off = 1; off < 128; off <<= 1) {
    int t = (tid >= off && tid < 128) ? lbase[tid - off] : 0;
    __syncthreads();
    if (tid < 128) lbase[tid] += t;
    __syncthreads();
  }
  if (tid < 128) {
    int excl = lbase[tid] - lcnt[tid];
    lbase[tid] = excl;
    int n = (b << BSH) + tid;
    if (n < N) {
      rowptr[n] = beg + excl;
      rowend[n] = beg + excl + lcnt[tid];
      int d = lcnt[tid];
      invd[n] = 1.0f / (float)(d > 1 ? d : 1);
    }
  }
  __syncthreads();
  for (int i = tid; i < cnt; i += 256) {
    uint32_t p = sp[i];
    int l = p & 127;
    int pos = beg + lbase[l] + atomicAdd(&lcur[l], 1);
    packed[pos] = p >> BSH;           // col value = src id
  }
}

// ---------------------------------------------------------------------------
// pass-1 mean aggregation over FP8 rows (128 B): quarter-wave per row,
// 8 B/lane, 16 edges/iter, branch-free zero-row padding. fp32 accumulate,
// bf16 output. emits the packed dropout mask (2 threefry + 2 ballots/node,
// hidden under gather latency).
// ---------------------------------------------------------------------------
__global__ __launch_bounds__(256) void agg_kernel(
    const uint8_t* __restrict__ xq, const int* __restrict__ rowptr,
    const int* __restrict__ rowend, const int* __restrict__ col,
    const float* __restrict__ invd, ushort* __restrict__ aggb,
    unsigned long long* __restrict__ maskb, int N) {
  const int lane = threadIdx.x & 63;
  const int q  = lane >> 4;            // quarter 0..3: edge slot
  const int sl = lane & 15;            // 8 B slice of the 128 B fp8 row
  const uint32_t slb = (uint32_t)sl * 8u;
  int n = (int)(((long)blockIdx.x * blockDim.x + threadIdx.x) >> 6);
  if (n >= N) return;

  {  // dropout mask for node n, packed 128 bits -> 2 x u64
    uint32_t base = (uint32_t)n * 128u;
    bool k0 = keep_bit(base + (uint32_t)lane);
    bool k1 = keep_bit(base + 64u + (uint32_t)lane);
    unsigned long long w0 = __ballot(k0);
    unsigned long long w1 = __ballot(k1);
    if (lane == 0) {
      maskb[2 * n]     = w0;
      maskb[2 * n + 1] = w1;
    }
  }

  const char* xc = (const char*)xq;
  const int beg = rowptr[n], end = rowend[n];
  const uint32_t zoff = ((uint32_t)N << 7) + slb;   // zero-row offset

  f32x2 acc[4];
#pragma unroll
  for (int i = 0; i < 4; i++) acc[i] = (f32x2){0.f, 0.f};

  for (int e = beg + q; e < end; e += 16) {
    int c0 = col[e], c1 = col[e + 4], c2 = col[e + 8], c3 = col[e + 12];
    uint32_t o0 = ((uint32_t)c0 << 7) + slb;
    uint32_t o1 = (e + 4  < end) ? (((uint32_t)c1 << 7) + slb) : zoff;
    uint32_t o2 = (e + 8  < end) ? (((uint32_t)c2 << 7) + slb) : zoff;
    uint32_t o3 = (e + 12 < end) ? (((uint32_t)c3 << 7) + slb) : zoff;
    uint2 a = *(const uint2*)(xc + o0);
    uint2 b = *(const uint2*)(xc + o1);
    uint2 c = *(const uint2*)(xc + o2);
    uint2 d = *(const uint2*)(xc + o3);
    accq(acc[0], acc[1], a.x); accq(acc[2], acc[3], a.y);
    accq(acc[0], acc[1], b.x); accq(acc[2], acc[3], b.y);
    accq(acc[0], acc[1], c.x); accq(acc[2], acc[3], c.y);
    accq(acc[0], acc[1], d.x); accq(acc[2], acc[3], d.y);
  }

#pragma unroll
  for (int i = 0; i < 4; i++) {
    acc[i].x += __shfl_xor(acc[i].x, 16);
    acc[i].y += __shfl_xor(acc[i].y, 16);
    acc[i].x += __shfl_xor(acc[i].x, 32);
    acc[i].y += __shfl_xor(acc[i].y, 32);
  }

  if (q == 0) {
    float sc = invd[n];
    ushort8 o;
#pragma unroll
    for (int i = 0; i < 4; i++) {
      o[2 * i]     = f2bf(acc[i].x * sc);
      o[2 * i + 1] = f2bf(acc[i].y * sc);
    }
    *(ushort8*)(aggb + (long)n * D_FEAT + sl * 8) = o;
  }
}

// ---------------------------------------------------------------------------
// fused layers, LDS kept <= 51200 B for 3 blocks/CU:
//  A1: stage w1[k<128] (32KB)  -> GEMM1 s=0..3 (agg path)
//  A2: stage w1[k>=128] (32KB) -> GEMM1 s=4..7 (x path)
//  B : h1 -> LDS (34816 B) + stage w2l (16KB) -> GEMM2-L (y2q)
//      restage w2r over w2l -> GEMM2-R (z); h1 A-frags held in VGPRs
// ---------------------------------------------------------------------------
__global__ __launch_bounds__(256) void fused12_kernel(
    const ushort* __restrict__ aggb, const ushort* __restrict__ xb,
    const ushort* __restrict__ w1t, const float* __restrict__ b1,
    const unsigned long long* __restrict__ maskb,
    const ushort* __restrict__ w2lt, const ushort* __restrict__ w2rt,
    const float* __restrict__ b2,
    uint8_t* __restrict__ y2q, ushort* __restrict__ z, int N) {
  __shared__ __align__(16) ushort smem[25600];   // 51200 B total
  ushort* w1s = smem;                 // phase A: 32 KB half [0, 32768) B
  ushort* h1s = smem;                 // phase B: [0, 34816) B, pitch H1P
  ushort* wb  = smem + 17408;         // phase B: [34816, 51200) B

  const int tid = threadIdx.x;
  const int lane = tid & 63;
  const int wv = tid >> 6;
  const int r16 = lane & 15;
  const int kg = lane >> 4;
  const uint32_t rswz = ((uint32_t)(r16 & 7)) << 4;

  // zero y2q phantom row (consumed by agg64 after this kernel)
  if (blockIdx.x == 0 && tid < 4)
    ((uint4*)(y2q + (long)N * D_OUT))[tid] = (uint4){0, 0, 0, 0};

  const int node_base = blockIdx.x * 128 + wv * 32;
  int ar0 = node_base + r16;       if (ar0 >= N) ar0 = N - 1;
  int ar1 = node_base + 16 + r16;  if (ar1 >= N) ar1 = N - 1;

  f32x4 acc0[8], acc1[8];
#pragma unroll
  for (int i = 0; i < 8; i++) {
    acc0[i] = (f32x4){0.f, 0.f, 0.f, 0.f};
    acc1[i] = (f32x4){0.f, 0.f, 0.f, 0.f};
  }

  // ---- phase A: two k-halves of w1 through one 32 KB buffer ----
#pragma unroll
  for (int h = 0; h < 2; h++) {
    {  // stage 128 rows x 256 B of this k-half; swizzle (row&7)<<4
#pragma unroll
      for (int i = 0; i < 8; i++) {
        uint32_t dst = (uint32_t)i * 4096u + (uint32_t)tid * 16u;
        uint32_t row = dst >> 8;
        uint4 v = *(const uint4*)((const char*)w1t +
                                  (row << 9) + (uint32_t)(h << 8) + (dst & 255u));
        *(uint4*)((char*)w1s + (dst ^ ((row & 7u) << 4))) = v;
      }
    }
    __syncthreads();
    const ushort* a0p = (h == 0 ? aggb : xb) + (long)ar0 * 128 + kg * 8;
    const ushort* a1p = (h == 0 ? aggb : xb) + (long)ar1 * 128 + kg * 8;
#pragma unroll
    for (int s = 0; s < 4; s++) {
      short8 aT0 = *(const short8*)(a0p + s * 32);
      short8 aT1 = *(const short8*)(a1p + s * 32);
#pragma unroll
      for (int ct = 0; ct < 8; ct++) {
        uint32_t boff = ((uint32_t)(ct * 16 + r16) * 256u +
                         (uint32_t)s * 64u + (uint32_t)kg * 16u) ^ rswz;
        short8 b = *(const short8*)((const char*)w1s + boff);
        acc0[ct] = __builtin_amdgcn_mfma_f32_16x16x32_bf16(aT0, b, acc0[ct], 0, 0, 0);
        acc1[ct] = __builtin_amdgcn_mfma_f32_16x16x32_bf16(aT1, b, acc1[ct], 0, 0, 0);
      }
    }
    __syncthreads();   // reads done before next stage / h1 write
  }

  // ---- phase B: h1 -> LDS, stage w2l concurrently ----
  {
    const uint32_t swz = ((uint32_t)(tid >> 4) & 7u) << 4;
#pragma unroll
    for (int i = 0; i < 4; i++) {
      uint32_t byte = (uint32_t)i * 4096u + (uint32_t)tid * 16u;
      uint4 vl = *(const uint4*)((const char*)w2lt + byte);
      *(uint4*)((char*)wb + (byte ^ swz)) = vl;
    }
  }
  {
    float bbv[8];
#pragma unroll
    for (int ct = 0; ct < 8; ct++) bbv[ct] = b1[ct * 16 + r16];
#pragma unroll
    for (int t = 0; t < 2; t++) {
      const f32x4* acc = t ? acc1 : acc0;
#pragma unroll
      for (int r = 0; r < 4; r++) {
        int row_l = wv * 32 + t * 16 + kg * 4 + r;
        int n = blockIdx.x * 128 + row_l;
        int mi = (n < N) ? n : (N - 1);
        unsigned long long m0 = maskb[2 * mi];
        unsigned long long m1 = maskb[2 * mi + 1];
        ushort* dst = h1s + row_l * H1P + r16;
#pragma unroll
        for (int ct = 0; ct < 8; ct++) {
          int j = ct * 16 + r16;
          float h = fmaxf(acc[ct][r] + bbv[ct], 0.f);
          unsigned long long w = (j & 64) ? m1 : m0;
          bool keep = (w >> (j & 63)) & 1ull;
          dst[ct * 16] = keep ? f2bf(2.0f * h) : (ushort)0;
        }
      }
    }
  }
  __syncthreads();

  // ---- read h1 A-fragments once into VGPRs (shared by both GEMM2 passes) ----
  short8 af[2][4];
#pragma unroll
  for (int t = 0; t < 2; t++)
#pragma unroll
    for (int s = 0; s < 4; s++)
      af[t][s] = *(const short8*)(h1s + (wv * 32 + t * 16 + r16) * H1P +
                                  s * 32 + kg * 8);

  // ---- GEMM2-L: y2 = h1 @ W2l (fp8 out) ----
  f32x4 aL[2][4];
#pragma unroll
  for (int t = 0; t < 2; t++)
#pragma unroll
    for (int i = 0; i < 4; i++) aL[t][i] = (f32x4){0.f, 0.f, 0.f, 0.f};
#pragma unroll
  for (int s = 0; s < 4; s++)
#pragma unroll
    for (int t = 0; t < 2; t++)
#pragma unroll
      for (int ct = 0; ct < 4; ct++) {
        uint32_t boff = ((uint32_t)(ct * 16 + r16) * 256u +
                         (uint32_t)s * 64u + (uint32_t)kg * 16u) ^ rswz;
        short8 bl = *(const short8*)((const char*)wb + boff);
        aL[t][ct] = __builtin_amdgcn_mfma_f32_16x16x32_bf16(af[t][s], bl, aL[t][ct], 0, 0, 0);
      }
  __syncthreads();   // wb reads done

  // ---- restage w2r, GEMM2-R: z = h1 @ W2r + b2 ----
  {
    const uint32_t swz = ((uint32_t)(tid >> 4) & 7u) << 4;
#pragma unroll
    for (int i = 0; i < 4; i++) {
      uint32_t byte = (uint32_t)i * 4096u + (uint32_t)tid * 16u;
      uint4 vr = *(const uint4*)((const char*)w2rt + byte);
      *(uint4*)((char*)wb + (byte ^ swz)) = vr;
    }
  }
  __syncthreads();

  f32x4 aR[2][4];
#pragma unroll
  for (int t = 0; t < 2; t++)
#pragma unroll
    for (int i = 0; i < 4; i++) aR[t][i] = (f32x4){0.f, 0.f, 0.f, 0.f};
#pragma unroll
  for (int s = 0; s < 4; s++)
#pragma unroll
    for (int t = 0; t < 2; t++)
#pragma unroll
      for (int ct = 0; ct < 4; ct++) {
        uint32_t boff = ((uint32_t)(ct * 16 + r16) * 256u +
                         (uint32_t)s * 64u + (uint32_t)kg * 16u) ^ rswz;
        short8 br = *(const short8*)((const char*)wb + boff);
        aR[t][ct] = __builtin_amdgcn_mfma_f32_16x16x32_bf16(af[t][s], br, aR[t][ct], 0, 0, 0);
      }

  float bb[4];
#pragma unroll
  for (int ct = 0; ct < 4; ct++) bb[ct] = b2[ct * 16 + r16];

#pragma unroll
  for (int t = 0; t < 2; t++) {
    int nb = node_base + t * 16;
#pragma unroll
    for (int r = 0; r < 4; r++) {
      int n = nb + kg * 4 + r;
      if (n < N) {
#pragma unroll
        for (int ct = 0; ct < 4; ct++) {
          float yv = aL[t][ct][r];
          int p = __builtin_amdgcn_cvt_pk_fp8_f32(yv, yv, 0, false);
          y2q[(long)n * D_OUT + ct * 16 + r16] = (uint8_t)p;
          z  [(long)n * D_OUT + ct * 16 + r16] = f2bf(aR[t][ct][r] + bb[ct]);
        }
      }
    }
  }
}

// ---------------------------------------------------------------------------
// pass-2 mean aggregation over FP8 y2 rows (64 B, eighth-wave per row) with
// FUSED log_softmax: out = logsm(z + mean(y2[src])). one wave per node.
// ---------------------------------------------------------------------------
__global__ __launch_bounds__(256) void agg64_kernel(
    const uint8_t* __restrict__ y2q, const ushort* __restrict__ z,
    const int* __restrict__ rowptr, const int* __restrict__ rowend,
    const int* __restrict__ col, const float* __restrict__ invd,
    float* __restrict__ out, int N) {
  const int lane = threadIdx.x & 63;
  const int g  = lane >> 3;            // oct 0..7
  const int sl = lane & 7;             // 8 B slice of the 64 B fp8 row
  const uint32_t slb = (uint32_t)sl * 8u;
  int n = (int)(((long)blockIdx.x * blockDim.x + threadIdx.x) >> 6);
  if (n >= N) return;

  const char* xc = (const char*)y2q;
  const int beg = rowptr[n], end = rowend[n];
  const uint32_t zoff = ((uint32_t)N << 6) + slb;

  f32x2 acc[4];
#pragma unroll
  for (int i = 0; i < 4; i++) acc[i] = (f32x2){0.f, 0.f};

  for (int e = beg + g; e < end; e += 16) {
    int c0 = col[e], c1 = col[e + 8];
    uint32_t o0 = ((uint32_t)c0 << 6) + slb;
    uint32_t o1 = (e + 8 < end) ? (((uint32_t)c1 << 6) + slb) : zoff;
    uint2 a = *(const uint2*)(xc + o0);
    uint2 b = *(const uint2*)(xc + o1);
    accq(acc[0], acc[1], a.x); accq(acc[2], acc[3], a.y);
    accq(acc[0], acc[1], b.x); accq(acc[2], acc[3], b.y);
  }

#pragma unroll
  for (int i = 0; i < 4; i++) {
    acc[i].x += __shfl_xor(acc[i].x, 8);
    acc[i].y += __shfl_xor(acc[i].y, 8);
    acc[i].x += __shfl_xor(acc[i].x, 16);
    acc[i].y += __shfl_xor(acc[i].y, 16);
    acc[i].x += __shfl_xor(acc[i].x, 32);
    acc[i].y += __shfl_xor(acc[i].y, 32);
  }

  if (g == 0) {   // lanes 0..7 hold the node's full 64-col row (8 each)
    float sc = invd[n];
    ushort8 zr = *(const ushort8*)(z + (long)n * D_OUT + sl * 8);
    float v[8];
#pragma unroll
    for (int i = 0; i < 4; i++) {
      v[2 * i]     = acc[i].x * sc + bf2f(zr[2 * i]);
      v[2 * i + 1] = acc[i].y * sc + bf2f(zr[2 * i + 1]);
    }
    float m = v[0];
#pragma unroll
    for (int j = 1; j < 8; j++) m = fmaxf(m, v[j]);
    m = fmaxf(m, __shfl_xor(m, 1));
    m = fmaxf(m, __shfl_xor(m, 2));
    m = fmaxf(m, __shfl_xor(m, 4));
    float s = 0.f;
#pragma unroll
    for (int j = 0; j < 8; j++) s += expf(v[j] - m);
    s += __shfl_xor(s, 1);
    s += __shfl_xor(s, 2);
    s += __shfl_xor(s, 4);
    float ls = m + logf(s);
    float4 o0 = {v[0] - ls, v[1] - ls, v[2] - ls, v[3] - ls};
    float4 o1 = {v[4] - ls, v[5] - ls, v[6] - ls, v[7] - ls};
    float* op = out + (long)n * D_OUT + sl * 8;
    *(float4*)op = o0;
    *(float4*)(op + 4) = o1;
  }
}

// ---------------------------------------------------------------------------
extern "C" void kernel_launch(void* const* d_in, const int* in_sizes, int n_in,
                              void* d_out, int out_size, void* d_ws, size_t ws_size,
                              hipStream_t stream) {
  const float* x   = (const float*)d_in[0];
  const void*  ei  = d_in[1];
  const float* W1l = (const float*)d_in[2];
  const float* b1  = (const float*)d_in[3];
  const float* W1r = (const float*)d_in[4];
  const float* W2l = (const float*)d_in[5];
  const float* b2  = (const float*)d_in[6];
  const float* W2r = (const float*)d_in[7];
  float* out = (float*)d_out;

  const int  N  = in_sizes[0] / D_FEAT;    // 100000
  const long E  = (long)in_sizes[1] / 2;   // 1600000
  const long NF = (long)N * D_FEAT;        // 12.8M
  const int  nbuck = (N + (1 << BSH) - 1) >> BSH;   // 782

  char* ws = (char*)d_ws;
  size_t off = 0;
  auto alloc = [&](size_t bytes) -> void* {
    void* p = ws + off;
    off = (off + bytes + 255) & ~(size_t)255;
    return p;
  };
  int*      bucketOff = (int*)alloc(sizeof(int) * MAXB);
  int*      rowptr    = (int*)alloc(sizeof(int) * N);
  int*      rowend    = (int*)alloc(sizeof(int) * N);
  uint32_t* packed    = (uint32_t*)alloc(sizeof(uint32_t) * ((size_t)nbuck * BCAP + 16));
  float*    invd      = (float*)alloc(sizeof(float) * N);
  ushort*   xb        = (ushort*)alloc(sizeof(ushort) * (NF + D_FEAT));   // +zero row
  uint8_t*  xq        = (uint8_t*)alloc(sizeof(uint8_t) * (NF + D_FEAT)); // fp8 +zero row; reused as y2q
  ushort*   aggb      = (ushort*)alloc(sizeof(ushort) * NF);
  ushort*   z         = (ushort*)alloc(sizeof(ushort) * ((size_t)N * D_OUT + 256));
  ushort*   w1t       = (ushort*)alloc(sizeof(ushort) * 128 * 256);
  ushort*   w2lt      = (ushort*)alloc(sizeof(ushort) * 64 * 128);
  ushort*   w2rt      = (ushort*)alloc(sizeof(ushort) * 64 * 128);
  unsigned long long* maskb = (unsigned long long*)alloc(sizeof(unsigned long long) * 2 * N);

  int* col = (int*)packed;          // col overwrites packed in place
  uint8_t* y2q = xq;                // xq is dead after agg1; reuse for fp8 y2

  const long n4 = NF / 4;                           // 3.2M float4 elements
  const int nConv = (int)((n4 + 255) / 256);        // 12500
  const int chunkE = (int)((E + SCAT_BLKS - 1) / SCAT_BLKS);
  const int prepBlocks = SCAT_BLKS + nConv + 128 + 64 + 1;

  hipMemsetAsync(bucketOff, 0, sizeof(int) * MAXB, stream);

  prep_kernel<<<prepBlocks, 256, 0, stream>>>(
      (const float4*)x, ei, xb, xq, W1l, W1r, W2l, W2r,
      w1t, w2lt, w2rt, bucketOff, packed,
      E, n4, N, nbuck, chunkE, nConv);

  bucket_build<<<nbuck, 256, 0, stream>>>(packed, bucketOff, rowptr, rowend, invd, N);

  const int aggBlocks = (int)(((long)N * 64 + 255) / 256);
  const int gemmBlocks = (N + 127) / 128;   // 782

  agg_kernel<<<aggBlocks, 256, 0, stream>>>(xq, rowptr, rowend, col, invd, aggb, maskb, N);
  fused12_kernel<<<gemmBlocks, 256, 0, stream>>>(aggb, xb, w1t, b1, maskb,
                                                 w2lt, w2rt, b2, y2q, z, N);
  agg64_kernel<<<aggBlocks, 256, 0, stream>>>(y2q, z, rowptr, rowend, col, invd, out, N);
}

// Round 20
// 178.994 us; speedup vs baseline: 1.0963x; 1.0963x over previous
//
#include <hip/hip_runtime.h>
#include <stdint.h>

#define D_FEAT 128
#define D_OUT  64
#define BSH 7              // 128 nodes per bucket
#define MAXB 1024          // max buckets (N <= 131072)
#define BCAP 4096          // fixed bucket capacity (mean 2046 + 45 sigma)
#define H1P  136           // h1 LDS row pitch in ushorts (272 B)
#define SCAT_BLKS 256      // prep-kernel blocks doing edge scatter
#define SCAT_CHUNK 6400    // max edges per scatter block (E/SCAT_BLKS padded)

typedef __attribute__((ext_vector_type(8))) short short8;   // 8 bf16 (4 VGPRs)
typedef __attribute__((ext_vector_type(8))) ushort ushort8; // 8 bf16
typedef __attribute__((ext_vector_type(4))) float f32x4;
typedef __attribute__((ext_vector_type(2))) float f32x2;

// ---------------------------------------------------------------------------
// helpers
// ---------------------------------------------------------------------------
__device__ __forceinline__ ushort f2bf(float f) {            // RNE f32->bf16
  uint32_t u = __float_as_uint(f);
  return (ushort)((u + 0x7FFFu + ((u >> 16) & 1u)) >> 16);
}
__device__ __forceinline__ float bf2f(ushort v) {
  return __uint_as_float((uint32_t)v << 16);
}
// accumulate a packed bf16 pair into an f32x2 (one v_pk_add_f32).
__device__ __forceinline__ void acc2(f32x2& a, uint32_t w) {
  f32x2 t;
  t.x = __uint_as_float(w << 16);
  t.y = __uint_as_float(w);
  a += t;
}
// accumulate 4 fp8 (one u32) into two f32x2 via native cvt
__device__ __forceinline__ void accq(f32x2& a, f32x2& b, uint32_t w) {
  a += __builtin_amdgcn_cvt_pk_f32_fp8(w, false);
  b += __builtin_amdgcn_cvt_pk_f32_fp8(w, true);
}

__device__ __forceinline__ void threefry2x32(uint32_t k0, uint32_t k1,
                                             uint32_t& x0, uint32_t& x1) {
  uint32_t k2 = k0 ^ k1 ^ 0x1BD11BDAu;
#define TF_ROT(r) { x0 += x1; x1 = (x1 << (r)) | (x1 >> (32 - (r))); x1 ^= x0; }
  x0 += k0; x1 += k1;
  TF_ROT(13) TF_ROT(15) TF_ROT(26) TF_ROT(6)
  x0 += k1; x1 += k2 + 1u;
  TF_ROT(17) TF_ROT(29) TF_ROT(16) TF_ROT(24)
  x0 += k2; x1 += k0 + 2u;
  TF_ROT(13) TF_ROT(15) TF_ROT(26) TF_ROT(6)
  x0 += k0; x1 += k1 + 3u;
  TF_ROT(17) TF_ROT(29) TF_ROT(16) TF_ROT(24)
  x0 += k1; x1 += k2 + 4u;
  TF_ROT(13) TF_ROT(15) TF_ROT(26) TF_ROT(6)
  x0 += k2; x1 += k0 + 5u;
#undef TF_ROT
}

__device__ __forceinline__ bool keep_bit(uint32_t i) {
  uint32_t t0 = 0u, t1 = i;
  threefry2x32(0u, 42u, t0, t1);
  return (((t0 ^ t1) >> 31) == 0u);
}

__device__ __forceinline__ int load_dst(const void* ei, int is64, long E, long e) {
  return is64 ? (int)((const long long*)ei)[E + e] : ((const int*)ei)[E + e];
}
__device__ __forceinline__ int load_src(const void* ei, int is64, long E, long e) {
  return is64 ? (int)((const long long*)ei)[e] : ((const int*)ei)[e];
}

// ---------------------------------------------------------------------------
// prep mega-kernel (grid-partitioned independent work):
//   blocks [0, SCAT_BLKS)            : edge scatter (single edge read; the
//                                      chunk's packed values + bucket ids are
//                                      cached in LDS between the two passes)
//   blocks [SCAT_BLKS, +nConv)       : x -> bf16 xb + fp8 xq
//   next 128 / 32 / 32 blocks        : pack w1 / w2l / w2r
//   last block                       : zero phantom rows of xb/xq
// bucketOff[] must be memset to 0 beforehand (cursors are bucket-relative).
// ---------------------------------------------------------------------------
__global__ __launch_bounds__(256) void prep_kernel(
    const float4* __restrict__ x, const void* __restrict__ ei,
    ushort* __restrict__ xb, uint8_t* __restrict__ xq,
    const float* __restrict__ W1l, const float* __restrict__ W1r,
    const float* __restrict__ W2l, const float* __restrict__ W2r,
    ushort* __restrict__ w1t, ushort* __restrict__ w2lt, ushort* __restrict__ w2rt,
    int* __restrict__ bucketOff, uint32_t* __restrict__ packed,
    long E, long n4, int N, int nbuck, int chunkE, int nConv) {
  __shared__ int cnt[MAXB];
  __shared__ int base[MAXB];
  __shared__ int cur[MAXB];
  __shared__ uint32_t sp[SCAT_CHUNK];
  __shared__ ushort sb[SCAT_CHUNK];
  __shared__ int is64_s;

  const int b = blockIdx.x;
  const int tid = threadIdx.x;

  if (b < SCAT_BLKS) {
    // ---- edge scatter (one global edge read) ----
    if (tid < 64) {
      uint32_t v = ((const uint32_t*)ei)[2 * tid + 1];
      unsigned long long nz = __ballot(v != 0u);
      if (tid == 0) is64_s = (nz == 0ull) ? 1 : 0;
    }
    for (int i = tid; i < nbuck; i += 256) { cnt[i] = 0; cur[i] = 0; }
    __syncthreads();
    const int is64 = is64_s;
    long beg = (long)b * chunkE;
    long end = beg + chunkE; if (end > E) end = E;
    const int cntE = (int)(end - beg);
    for (int i = tid; i < cntE; i += 256) {
      long e = beg + i;
      int dst = load_dst(ei, is64, E, e);
      int src = load_src(ei, is64, E, e);
      int bk = dst >> BSH;
      sp[i] = ((uint32_t)src << BSH) | (uint32_t)(dst & ((1 << BSH) - 1));
      sb[i] = (ushort)bk;
      atomicAdd(&cnt[bk], 1);
    }
    __syncthreads();
    for (int i = tid; i < nbuck; i += 256)
      base[i] = cnt[i] ? atomicAdd(&bucketOff[i], cnt[i]) : 0;
    __syncthreads();
    for (int i = tid; i < cntE; i += 256) {
      int bk = sb[i];
      int off = atomicAdd(&cur[bk], 1);
      packed[(long)bk * BCAP + base[bk] + off] = sp[i];
    }
  } else if (b < SCAT_BLKS + nConv) {
    // ---- convert x -> bf16 + fp8 ----
    long i = (long)(b - SCAT_BLKS) * 256 + tid;
    if (i < n4) {
      float4 v = x[i];
      ushort4 o = {f2bf(v.x), f2bf(v.y), f2bf(v.z), f2bf(v.w)};
      *(ushort4*)(xb + i * 4) = o;
      int p = 0;
      p = __builtin_amdgcn_cvt_pk_fp8_f32(v.x, v.y, p, false);
      p = __builtin_amdgcn_cvt_pk_fp8_f32(v.z, v.w, p, true);
      ((uint32_t*)xq)[i] = (uint32_t)p;
    }
  } else if (b < SCAT_BLKS + nConv + 128) {
    // ---- pack w1: w1t[j][k] ----
    int idx = (b - SCAT_BLKS - nConv) * 256 + tid;   // 128*256
    int j = idx >> 8, k = idx & 255;
    float v = (k < 128) ? W1l[k * 128 + j] : W1r[(k - 128) * 128 + j];
    w1t[j * 256 + k] = f2bf(v);
  } else if (b < SCAT_BLKS + nConv + 128 + 32) {
    int idx = (b - SCAT_BLKS - nConv - 128) * 256 + tid;   // 64*128
    int j = idx >> 7, k = idx & 127;
    w2lt[j * 128 + k] = f2bf(W2l[k * 64 + j]);
  } else if (b < SCAT_BLKS + nConv + 128 + 64) {
    int idx = (b - SCAT_BLKS - nConv - 160) * 256 + tid;
    int j = idx >> 7, k = idx & 127;
    w2rt[j * 128 + k] = f2bf(W2r[k * 64 + j]);
  } else {
    // ---- zero phantom rows (xb bf16 256 B, xq fp8 128 B) ----
    if (tid < 16)
      *(ushort8*)(xb + (long)N * D_FEAT + tid * 8) = (ushort8){0,0,0,0,0,0,0,0};
    else if (tid < 24)
      *(uint4*)(xq + (long)N * D_FEAT + (tid - 16) * 16) = (uint4){0,0,0,0};
  }
}

// ---------------------------------------------------------------------------
// per bucket: stage to LDS -> local hist+scan -> rowptr/rowend/invd,
// then write col IN PLACE over packed (values become src ids)
// ---------------------------------------------------------------------------
__global__ __launch_bounds__(256) void bucket_build(
    uint32_t* __restrict__ packed, const int* __restrict__ bucketOff,
    int* __restrict__ rowptr, int* __restrict__ rowend,
    float* __restrict__ invd, int N) {
  __shared__ uint32_t sp[BCAP];
  __shared__ int lcnt[1 << BSH];
  __shared__ int lbase[1 << BSH];
  __shared__ int lcur[1 << BSH];
  const int b = blockIdx.x;
  const int tid = threadIdx.x;
  const int beg = b * BCAP;
  const int cnt = bucketOff[b];
  for (int i = tid; i < cnt; i += 256) sp[i] = packed[beg + i];
  if (tid < 128) { lcnt[tid] = 0; lcur[tid] = 0; }
  __syncthreads();
  for (int i = tid; i < cnt; i += 256)
    atomicAdd(&lcnt[sp[i] & 127], 1);
  __syncthreads();
  if (tid < 128) lbase[tid] = lcnt[tid];
  __syncthreads();
  for (int off = 1; off < 128; off <<= 1) {
    int t = (tid >= off && tid < 128) ? lbase[tid - off] : 0;
    __syncthreads();
    if (tid < 128) lbase[tid] += t;
    __syncthreads();
  }
  if (tid < 128) {
    int excl = lbase[tid] - lcnt[tid];
    lbase[tid] = excl;
    int n = (b << BSH) + tid;
    if (n < N) {
      rowptr[n] = beg + excl;
      rowend[n] = beg + excl + lcnt[tid];
      int d = lcnt[tid];
      invd[n] = 1.0f / (float)(d > 1 ? d : 1);
    }
  }
  __syncthreads();
  for (int i = tid; i < cnt; i += 256) {
    uint32_t p = sp[i];
    int l = p & 127;
    int pos = beg + lbase[l] + atomicAdd(&lcur[l], 1);
    packed[pos] = p >> BSH;           // col value = src id
  }
}

// ---------------------------------------------------------------------------
// pass-1 mean aggregation over FP8 rows (128 B): quarter-wave per row,
// 8 B/lane, 16 edges/iter, branch-free zero-row padding. fp32 accumulate,
// bf16 output. emits the packed dropout mask (2 threefry + 2 ballots/node,
// hidden under gather latency).
// ---------------------------------------------------------------------------
__global__ __launch_bounds__(256) void agg_kernel(
    const uint8_t* __restrict__ xq, const int* __restrict__ rowptr,
    const int* __restrict__ rowend, const int* __restrict__ col,
    const float* __restrict__ invd, ushort* __restrict__ aggb,
    unsigned long long* __restrict__ maskb, int N) {
  const int lane = threadIdx.x & 63;
  const int q  = lane >> 4;            // quarter 0..3: edge slot
  const int sl = lane & 15;            // 8 B slice of the 128 B fp8 row
  const uint32_t slb = (uint32_t)sl * 8u;
  int n = (int)(((long)blockIdx.x * blockDim.x + threadIdx.x) >> 6);
  if (n >= N) return;

  {  // dropout mask for node n, packed 128 bits -> 2 x u64
    uint32_t base = (uint32_t)n * 128u;
    bool k0 = keep_bit(base + (uint32_t)lane);
    bool k1 = keep_bit(base + 64u + (uint32_t)lane);
    unsigned long long w0 = __ballot(k0);
    unsigned long long w1 = __ballot(k1);
    if (lane == 0) {
      maskb[2 * n]     = w0;
      maskb[2 * n + 1] = w1;
    }
  }

  const char* xc = (const char*)xq;
  const int beg = rowptr[n], end = rowend[n];
  const uint32_t zoff = ((uint32_t)N << 7) + slb;   // zero-row offset

  f32x2 acc[4];
#pragma unroll
  for (int i = 0; i < 4; i++) acc[i] = (f32x2){0.f, 0.f};

  for (int e = beg + q; e < end; e += 16) {
    int c0 = col[e], c1 = col[e + 4], c2 = col[e + 8], c3 = col[e + 12];
    uint32_t o0 = ((uint32_t)c0 << 7) + slb;
    uint32_t o1 = (e + 4  < end) ? (((uint32_t)c1 << 7) + slb) : zoff;
    uint32_t o2 = (e + 8  < end) ? (((uint32_t)c2 << 7) + slb) : zoff;
    uint32_t o3 = (e + 12 < end) ? (((uint32_t)c3 << 7) + slb) : zoff;
    uint2 a = *(const uint2*)(xc + o0);
    uint2 b = *(const uint2*)(xc + o1);
    uint2 c = *(const uint2*)(xc + o2);
    uint2 d = *(const uint2*)(xc + o3);
    accq(acc[0], acc[1], a.x); accq(acc[2], acc[3], a.y);
    accq(acc[0], acc[1], b.x); accq(acc[2], acc[3], b.y);
    accq(acc[0], acc[1], c.x); accq(acc[2], acc[3], c.y);
    accq(acc[0], acc[1], d.x); accq(acc[2], acc[3], d.y);
  }

#pragma unroll
  for (int i = 0; i < 4; i++) {
    acc[i].x += __shfl_xor(acc[i].x, 16);
    acc[i].y += __shfl_xor(acc[i].y, 16);
    acc[i].x += __shfl_xor(acc[i].x, 32);
    acc[i].y += __shfl_xor(acc[i].y, 32);
  }

  if (q == 0) {
    float sc = invd[n];
    ushort8 o;
#pragma unroll
    for (int i = 0; i < 4; i++) {
      o[2 * i]     = f2bf(acc[i].x * sc);
      o[2 * i + 1] = f2bf(acc[i].y * sc);
    }
    *(ushort8*)(aggb + (long)n * D_FEAT + sl * 8) = o;
  }
}

// ---------------------------------------------------------------------------
// fused layers (R18 layout): GEMM1 (h1 = dropout(relu([agg|x]@W1+b1))) in LDS,
// then GEMM2 dual (y2q = fp8(h1@W2l), z = bf16(h1@W2r + b2)).
// ---------------------------------------------------------------------------
__global__ __launch_bounds__(256) void fused12_kernel(
    const ushort* __restrict__ aggb, const ushort* __restrict__ xb,
    const ushort* __restrict__ w1t, const float* __restrict__ b1,
    const unsigned long long* __restrict__ maskb,
    const ushort* __restrict__ w2lt, const ushort* __restrict__ w2rt,
    const float* __restrict__ b2,
    uint8_t* __restrict__ y2q, ushort* __restrict__ z, int N) {
  __shared__ __align__(16) ushort smem[33792];   // 67584 B
  ushort* w1s = smem;                 // phase A: [0, 65536) B
  ushort* h1s = smem;                 // phase B: [0, 34816) B, pitch H1P
  ushort* wsl = smem + 17408;         // [34816, 51200) B
  ushort* wsr = smem + 25600;         // [51200, 67584) B

  const int tid = threadIdx.x;
  const int lane = tid & 63;
  const int wv = tid >> 6;
  const int r16 = lane & 15;
  const int kg = lane >> 4;

  // zero y2q phantom row (consumed by agg64 after this kernel)
  if (blockIdx.x == 0 && tid < 4)
    ((uint4*)(y2q + (long)N * D_OUT))[tid] = (uint4){0, 0, 0, 0};

  // ---- phase A: stage w1 (swizzle for 512 B rows) ----
  {
    const uint32_t swz = ((uint32_t)(tid >> 5) & 7u) << 4;
#pragma unroll
    for (int i = 0; i < 16; i++) {
      uint32_t byte = (uint32_t)i * 4096u + (uint32_t)tid * 16u;
      uint4 v = *(const uint4*)((const char*)w1t + byte);
      *(uint4*)((char*)w1s + (byte ^ swz)) = v;
    }
  }
  __syncthreads();

  const int node_base = blockIdx.x * 128 + wv * 32;
  int ar0 = node_base + r16;       if (ar0 >= N) ar0 = N - 1;
  int ar1 = node_base + 16 + r16;  if (ar1 >= N) ar1 = N - 1;

  f32x4 acc0[8], acc1[8];
#pragma unroll
  for (int i = 0; i < 8; i++) {
    acc0[i] = (f32x4){0.f, 0.f, 0.f, 0.f};
    acc1[i] = (f32x4){0.f, 0.f, 0.f, 0.f};
  }

  {
    const ushort* a0g = aggb + (long)ar0 * 128 + kg * 8;
    const ushort* a0x = xb   + (long)ar0 * 128 + kg * 8;
    const ushort* a1g = aggb + (long)ar1 * 128 + kg * 8;
    const ushort* a1x = xb   + (long)ar1 * 128 + kg * 8;
    const uint32_t rswz = ((uint32_t)(r16 & 7)) << 4;
#pragma unroll
    for (int s = 0; s < 8; s++) {
      short8 aT0 = (s < 4) ? *(const short8*)(a0g + s * 32)
                           : *(const short8*)(a0x + (s - 4) * 32);
      short8 aT1 = (s < 4) ? *(const short8*)(a1g + s * 32)
                           : *(const short8*)(a1x + (s - 4) * 32);
#pragma unroll
      for (int ct = 0; ct < 8; ct++) {
        uint32_t boff = ((uint32_t)(ct * 16 + r16) * 512u +
                         (uint32_t)s * 64u + (uint32_t)kg * 16u) ^ rswz;
        short8 b = *(const short8*)((const char*)w1s + boff);
        acc0[ct] = __builtin_amdgcn_mfma_f32_16x16x32_bf16(aT0, b, acc0[ct], 0, 0, 0);
        acc1[ct] = __builtin_amdgcn_mfma_f32_16x16x32_bf16(aT1, b, acc1[ct], 0, 0, 0);
      }
    }
  }
  __syncthreads();   // all w1s reads complete before overwrite

  // ---- phase B setup: stage w2l/w2r + h1 -> LDS ----
  {
    const uint32_t swz = ((uint32_t)(tid >> 4) & 7u) << 4;
#pragma unroll
    for (int i = 0; i < 4; i++) {
      uint32_t byte = (uint32_t)i * 4096u + (uint32_t)tid * 16u;
      uint4 vl = *(const uint4*)((const char*)w2lt + byte);
      uint4 vr = *(const uint4*)((const char*)w2rt + byte);
      *(uint4*)((char*)wsl + (byte ^ swz)) = vl;
      *(uint4*)((char*)wsr + (byte ^ swz)) = vr;
    }
  }

  {
    float bbv[8];
#pragma unroll
    for (int ct = 0; ct < 8; ct++) bbv[ct] = b1[ct * 16 + r16];
#pragma unroll
    for (int t = 0; t < 2; t++) {
      const f32x4* acc = t ? acc1 : acc0;
#pragma unroll
      for (int r = 0; r < 4; r++) {
        int row_l = wv * 32 + t * 16 + kg * 4 + r;
        int n = blockIdx.x * 128 + row_l;
        int mi = (n < N) ? n : (N - 1);
        unsigned long long m0 = maskb[2 * mi];
        unsigned long long m1 = maskb[2 * mi + 1];
        ushort* dst = h1s + row_l * H1P + r16;
#pragma unroll
        for (int ct = 0; ct < 8; ct++) {
          int j = ct * 16 + r16;
          float h = fmaxf(acc[ct][r] + bbv[ct], 0.f);
          unsigned long long w = (j & 64) ? m1 : m0;
          bool keep = (w >> (j & 63)) & 1ull;
          dst[ct * 16] = keep ? f2bf(2.0f * h) : (ushort)0;
        }
      }
    }
  }
  __syncthreads();

  // ---- GEMM2: A from h1s, B from wsl/wsr ----
  f32x4 aL[2][4], aR[2][4];
#pragma unroll
  for (int t = 0; t < 2; t++)
#pragma unroll
    for (int i = 0; i < 4; i++) {
      aL[t][i] = (f32x4){0.f, 0.f, 0.f, 0.f};
      aR[t][i] = (f32x4){0.f, 0.f, 0.f, 0.f};
    }

  {
    const uint32_t rswz = ((uint32_t)(r16 & 7)) << 4;
#pragma unroll
    for (int s = 0; s < 4; s++) {
#pragma unroll
      for (int t = 0; t < 2; t++) {
        const ushort* ap = h1s + (wv * 32 + t * 16 + r16) * H1P + s * 32 + kg * 8;
        short8 a = *(const short8*)ap;
#pragma unroll
        for (int ct = 0; ct < 4; ct++) {
          uint32_t boff = ((uint32_t)(ct * 16 + r16) * 256u +
                           (uint32_t)s * 64u + (uint32_t)kg * 16u) ^ rswz;
          short8 bl = *(const short8*)((const char*)wsl + boff);
          short8 br = *(const short8*)((const char*)wsr + boff);
          aL[t][ct] = __builtin_amdgcn_mfma_f32_16x16x32_bf16(a, bl, aL[t][ct], 0, 0, 0);
          aR[t][ct] = __builtin_amdgcn_mfma_f32_16x16x32_bf16(a, br, aR[t][ct], 0, 0, 0);
        }
      }
    }
  }

  float bb[4];
#pragma unroll
  for (int ct = 0; ct < 4; ct++) bb[ct] = b2[ct * 16 + r16];

#pragma unroll
  for (int t = 0; t < 2; t++) {
    int nb = node_base + t * 16;
#pragma unroll
    for (int r = 0; r < 4; r++) {
      int n = nb + kg * 4 + r;
      if (n < N) {
#pragma unroll
        for (int ct = 0; ct < 4; ct++) {
          float yv = aL[t][ct][r];
          int p = __builtin_amdgcn_cvt_pk_fp8_f32(yv, yv, 0, false);
          y2q[(long)n * D_OUT + ct * 16 + r16] = (uint8_t)p;
          z  [(long)n * D_OUT + ct * 16 + r16] = f2bf(aR[t][ct][r] + bb[ct]);
        }
      }
    }
  }
}

// ---------------------------------------------------------------------------
// pass-2 mean aggregation over FP8 y2 rows (64 B, eighth-wave per row) with
// FUSED log_softmax: out = logsm(z + mean(y2[src])). one wave per node.
// ---------------------------------------------------------------------------
__global__ __launch_bounds__(256) void agg64_kernel(
    const uint8_t* __restrict__ y2q, const ushort* __restrict__ z,
    const int* __restrict__ rowptr, const int* __restrict__ rowend,
    const int* __restrict__ col, const float* __restrict__ invd,
    float* __restrict__ out, int N) {
  const int lane = threadIdx.x & 63;
  const int g  = lane >> 3;            // oct 0..7
  const int sl = lane & 7;             // 8 B slice of the 64 B fp8 row
  const uint32_t slb = (uint32_t)sl * 8u;
  int n = (int)(((long)blockIdx.x * blockDim.x + threadIdx.x) >> 6);
  if (n >= N) return;

  const char* xc = (const char*)y2q;
  const int beg = rowptr[n], end = rowend[n];
  const uint32_t zoff = ((uint32_t)N << 6) + slb;

  f32x2 acc[4];
#pragma unroll
  for (int i = 0; i < 4; i++) acc[i] = (f32x2){0.f, 0.f};

  for (int e = beg + g; e < end; e += 16) {
    int c0 = col[e], c1 = col[e + 8];
    uint32_t o0 = ((uint32_t)c0 << 6) + slb;
    uint32_t o1 = (e + 8 < end) ? (((uint32_t)c1 << 6) + slb) : zoff;
    uint2 a = *(const uint2*)(xc + o0);
    uint2 b = *(const uint2*)(xc + o1);
    accq(acc[0], acc[1], a.x); accq(acc[2], acc[3], a.y);
    accq(acc[0], acc[1], b.x); accq(acc[2], acc[3], b.y);
  }

#pragma unroll
  for (int i = 0; i < 4; i++) {
    acc[i].x += __shfl_xor(acc[i].x, 8);
    acc[i].y += __shfl_xor(acc[i].y, 8);
    acc[i].x += __shfl_xor(acc[i].x, 16);
    acc[i].y += __shfl_xor(acc[i].y, 16);
    acc[i].x += __shfl_xor(acc[i].x, 32);
    acc[i].y += __shfl_xor(acc[i].y, 32);
  }

  if (g == 0) {   // lanes 0..7 hold the node's full 64-col row (8 each)
    float sc = invd[n];
    ushort8 zr = *(const ushort8*)(z + (long)n * D_OUT + sl * 8);
    float v[8];
#pragma unroll
    for (int i = 0; i < 4; i++) {
      v[2 * i]     = acc[i].x * sc + bf2f(zr[2 * i]);
      v[2 * i + 1] = acc[i].y * sc + bf2f(zr[2 * i + 1]);
    }
    float m = v[0];
#pragma unroll
    for (int j = 1; j < 8; j++) m = fmaxf(m, v[j]);
    m = fmaxf(m, __shfl_xor(m, 1));
    m = fmaxf(m, __shfl_xor(m, 2));
    m = fmaxf(m, __shfl_xor(m, 4));
    float s = 0.f;
#pragma unroll
    for (int j = 0; j < 8; j++) s += expf(v[j] - m);
    s += __shfl_xor(s, 1);
    s += __shfl_xor(s, 2);
    s += __shfl_xor(s, 4);
    float ls = m + logf(s);
    float4 o0 = {v[0] - ls, v[1] - ls, v[2] - ls, v[3] - ls};
    float4 o1 = {v[4] - ls, v[5] - ls, v[6] - ls, v[7] - ls};
    float* op = out + (long)n * D_OUT + sl * 8;
    *(float4*)op = o0;
    *(float4*)(op + 4) = o1;
  }
}

// ---------------------------------------------------------------------------
extern "C" void kernel_launch(void* const* d_in, const int* in_sizes, int n_in,
                              void* d_out, int out_size, void* d_ws, size_t ws_size,
                              hipStream_t stream) {
  const float* x   = (const float*)d_in[0];
  const void*  ei  = d_in[1];
  const float* W1l = (const float*)d_in[2];
  const float* b1  = (const float*)d_in[3];
  const float* W1r = (const float*)d_in[4];
  const float* W2l = (const float*)d_in[5];
  const float* b2  = (const float*)d_in[6];
  const float* W2r = (const float*)d_in[7];
  float* out = (float*)d_out;

  const int  N  = in_sizes[0] / D_FEAT;    // 100000
  const long E  = (long)in_sizes[1] / 2;   // 1600000
  const long NF = (long)N * D_FEAT;        // 12.8M
  const int  nbuck = (N + (1 << BSH) - 1) >> BSH;   // 782

  char* ws = (char*)d_ws;
  size_t off = 0;
  auto alloc = [&](size_t bytes) -> void* {
    void* p = ws + off;
    off = (off + bytes + 255) & ~(size_t)255;
    return p;
  };
  int*      bucketOff = (int*)alloc(sizeof(int) * MAXB);
  int*      rowptr    = (int*)alloc(sizeof(int) * N);
  int*      rowend    = (int*)alloc(sizeof(int) * N);
  uint32_t* packed    = (uint32_t*)alloc(sizeof(uint32_t) * ((size_t)nbuck * BCAP + 16));
  float*    invd      = (float*)alloc(sizeof(float) * N);
  ushort*   xb        = (ushort*)alloc(sizeof(ushort) * (NF + D_FEAT));   // +zero row
  uint8_t*  xq        = (uint8_t*)alloc(sizeof(uint8_t) * (NF + D_FEAT)); // fp8 +zero row; reused as y2q
  ushort*   aggb      = (ushort*)alloc(sizeof(ushort) * NF);
  ushort*   z         = (ushort*)alloc(sizeof(ushort) * ((size_t)N * D_OUT + 256));
  ushort*   w1t       = (ushort*)alloc(sizeof(ushort) * 128 * 256);
  ushort*   w2lt      = (ushort*)alloc(sizeof(ushort) * 64 * 128);
  ushort*   w2rt      = (ushort*)alloc(sizeof(ushort) * 64 * 128);
  unsigned long long* maskb = (unsigned long long*)alloc(sizeof(unsigned long long) * 2 * N);

  int* col = (int*)packed;          // col overwrites packed in place
  uint8_t* y2q = xq;                // xq is dead after agg1; reuse for fp8 y2

  const long n4 = NF / 4;                           // 3.2M float4 elements
  const int nConv = (int)((n4 + 255) / 256);        // 12500
  const int chunkE = (int)((E + SCAT_BLKS - 1) / SCAT_BLKS);  // 6250 <= SCAT_CHUNK
  const int prepBlocks = SCAT_BLKS + nConv + 128 + 64 + 1;

  hipMemsetAsync(bucketOff, 0, sizeof(int) * MAXB, stream);

  prep_kernel<<<prepBlocks, 256, 0, stream>>>(
      (const float4*)x, ei, xb, xq, W1l, W1r, W2l, W2r,
      w1t, w2lt, w2rt, bucketOff, packed,
      E, n4, N, nbuck, chunkE, nConv);

  bucket_build<<<nbuck, 256, 0, stream>>>(packed, bucketOff, rowptr, rowend, invd, N);

  const int aggBlocks = (int)(((long)N * 64 + 255) / 256);
  const int gemmBlocks = (N + 127) / 128;   // 782

  agg_kernel<<<aggBlocks, 256, 0, stream>>>(xq, rowptr, rowend, col, invd, aggb, maskb, N);
  fused12_kernel<<<gemmBlocks, 256, 0, stream>>>(aggb, xb, w1t, b1, maskb,
                                                 w2lt, w2rt, b2, y2q, z, N);
  agg64_kernel<<<aggBlocks, 256, 0, stream>>>(y2q, z, rowptr, rowend, col, invd, out, N);
}